// Round 4
// baseline (293.817 us; speedup 1.0000x reference)
//
#include <hip/hip_runtime.h>

#define N_NODES 100000
#define N_EDGES 1600000
#define D_FEAT  64

#define MAXD   64                               // ELL slots per row (Poisson(16): max deg ~40)
#define EPB    4096                             // edges per scatter block
#define SCB    ((N_EDGES + EPB - 1) / EPB)      // 391 scatter blocks
#define CVB    ((N_NODES * D_FEAT / 4 + 1023) / 1024)  // 1563 convert blocks

typedef float f32x2 __attribute__((ext_vector_type(2)));

__device__ __forceinline__ unsigned short f2bf(float f) {
  union { float f; unsigned int i; } v; v.f = f;
  unsigned int b = v.i;
  return (unsigned short)((b + 0x7FFFu + ((b >> 16) & 1u)) >> 16);  // RNE
}
__device__ __forceinline__ float ulo(int u) { return __int_as_float(u << 16); }
__device__ __forceinline__ float uhi(int u) { return __int_as_float(u & 0xFFFF0000); }
__device__ __forceinline__ f32x2 upk(int u) {  // {elem0, elem1} of a bf16 pair
  f32x2 r; r.x = ulo(u); r.y = uhi(u); return r;
}
__device__ __forceinline__ int pk(float a, float b) {
  return (int)f2bf(a) | ((int)f2bf(b) << 16);
}

// ---- fused single-pass prep: blocks [0,SCB) scatter edges directly into the
// ELL table (slot = atomicAdd of the row counter); blocks [SCB,SCB+CVB)
// convert x to bf16. Replaces the old two-pass bucketed-CSR build (bin ->
// scan -> scatter -> histogram -> scan -> scatter) with one edge pass.
__global__ __launch_bounds__(1024) void scatter_convert(
    const float4* __restrict__ xin, ushort4* __restrict__ xout,
    const int* __restrict__ erow, const int* __restrict__ ecol,
    const float* __restrict__ evals, int2* __restrict__ ell,
    int* __restrict__ cnt) {
  int t = threadIdx.x;
  int k = blockIdx.x;
  if (k >= SCB) {                        // ---- convert path ----
    int i = (k - SCB) * 1024 + t;
    if (i < N_NODES * D_FEAT / 4) {
      float4 v = xin[i];
      ushort4 o;
      o.x = f2bf(v.x); o.y = f2bf(v.y); o.z = f2bf(v.z); o.w = f2bf(v.w);
      xout[i] = o;
    }
    return;
  }
  // ---- scatter path: 4096 edges, 4 per thread, no LDS, no syncs ----
  int base = k * EPB;
  int nk = N_EDGES - base; if (nk > EPB) nk = EPB;
#pragma unroll
  for (int j = 0; j < 4; ++j) {
    int li = j * 1024 + t;
    if (li < nk) {
      int e = base + li;
      int r = erow[e];
      int slot = atomicAdd(&cnt[r], 1);
      if (slot < MAXD)                   // defensive; P(overflow) ~ 1e-19
        ell[r * MAXD + slot] = make_int2(ecol[e], __float_as_int(evals[e]));
    }
  }
}

// ---- pad odd-degree rows with a {0,0} pair-slot so spmm can read whole
// int4 pairs (pad contributes val=0 * x[0] = 0). Also clamps cnt (paranoia).
__global__ __launch_bounds__(256) void pad_ell(int2* __restrict__ ell,
                                               int* __restrict__ cnt) {
  int r = blockIdx.x * 256 + threadIdx.x;
  if (r < N_NODES) {
    int c = cnt[r];
    if (c > MAXD) { c = MAXD; cnt[r] = c; }
    if (c & 1) ell[r * MAXD + c] = make_int2(0, 0);
  }
}

// ---- SpMM: ONE OCTET PER ROW (8 lanes x int4 = the full 128B feature row).
// 8 consecutive rows per wave, zero shuffles, zero LDS. Per edge pair: one
// int4 octet-broadcast edge load + two int4 x-gathers; 2-pair unroll for MLP.
// Row base is row*MAXD (even -> 16B-aligned pairs).
__global__ __launch_bounds__(256) void spmm_oct(
    const int* __restrict__ cnt, const int2* __restrict__ ell,
    const int4* __restrict__ xq, int4* __restrict__ h_q,
    float4* __restrict__ out, const int4* __restrict__ add1,
    const int4* __restrict__ add2, int final_mode) {
  int t = threadIdx.x;
  int lane = t & 63;
  int oct = lane >> 3;     // 0..7: row within wave
  int ol  = lane & 7;      // 0..7: which 16B of the 128B row
  int row = blockIdx.x * 32 + (t >> 6) * 8 + oct;   // grid exact: 3125*32=100000
  const int4* ep = (const int4*)(ell + row * MAXD);
  // Round UP: odd lengths include the (real, pad) pair; pad {0,0} adds 0.
  int npair = (cnt[row] + 1) >> 1;
  f32x2 c0 = {0.f, 0.f}, c1 = {0.f, 0.f}, c2 = {0.f, 0.f}, c3 = {0.f, 0.f};

#define PAIR(m) { \
    int4 g0 = xq[(size_t)(m).x * 8 + ol]; \
    int4 g1 = xq[(size_t)(m).z * 8 + ol]; \
    float v0 = __int_as_float((m).y), v1 = __int_as_float((m).w); \
    f32x2 vv0 = {v0, v0}, vv1 = {v1, v1}; \
    c0 += vv0 * upk(g0.x) + vv1 * upk(g1.x); \
    c1 += vv0 * upk(g0.y) + vv1 * upk(g1.y); \
    c2 += vv0 * upk(g0.z) + vv1 * upk(g1.z); \
    c3 += vv0 * upk(g0.w) + vv1 * upk(g1.w); \
  }

  int p = 0;
  for (; p + 2 <= npair; p += 2) {   // 2 pairs = 4 edges: 6 loads in flight
    int4 m0 = ep[p];
    int4 m1 = ep[p + 1];
    PAIR(m0);
    PAIR(m1);
  }
  if (p < npair) {
    int4 m0 = ep[p];
    PAIR(m0);
  }
#undef PAIR

  size_t oi = (size_t)row * 8 + ol;
  if (final_mode) {
    int4 r1 = add1[oi];
    int4 r2 = add2[oi];
    float4 lo, hi;
    lo.x = c0.x + ulo(r1.x) + ulo(r2.x);
    lo.y = c0.y + uhi(r1.x) + uhi(r2.x);
    lo.z = c1.x + ulo(r1.y) + ulo(r2.y);
    lo.w = c1.y + uhi(r1.y) + uhi(r2.y);
    hi.x = c2.x + ulo(r1.z) + ulo(r2.z);
    hi.y = c2.y + uhi(r1.z) + uhi(r2.z);
    hi.z = c3.x + ulo(r1.w) + ulo(r2.w);
    hi.w = c3.y + uhi(r1.w) + uhi(r2.w);
    out[(size_t)row * 16 + ol * 2]     = lo;
    out[(size_t)row * 16 + ol * 2 + 1] = hi;
  } else {
    int4 pq;
    pq.x = pk(c0.x, c0.y);
    pq.y = pk(c1.x, c1.y);
    pq.z = pk(c2.x, c2.y);
    pq.w = pk(c3.x, c3.y);
    h_q[oi] = pq;
  }
}

extern "C" void kernel_launch(void* const* d_in, const int* in_sizes, int n_in,
                              void* d_out, int out_size, void* d_ws, size_t ws_size,
                              hipStream_t stream) {
  const float* x     = (const float*)d_in[0];
  const int*   erow  = (const int*)d_in[1];
  const int*   ecol  = (const int*)d_in[2];
  const float* evals = (const float*)d_in[3];
  float* out = (float*)d_out;

  const size_t hb_bytes  = (size_t)N_NODES * D_FEAT * 2;       // 12.8 MB (bf16)
  const size_t ell_bytes = (size_t)N_NODES * MAXD * sizeof(int2); // 51.2 MB
  char* ws = (char*)d_ws;
  int4* xbf  = (int4*)(ws);                       // 12.8 MB, live whole launch
  int4* bufA = (int4*)(ws + hb_bytes);            // h1 (bf16)
  int4* bufB = (int4*)(ws + 2 * hb_bytes);        // h2 (bf16)
  int2* ell  = (int2*)(ws + 3 * hb_bytes);        // 51.2 MB ELL edge table
  int*  cnt  = (int*) (ws + 3 * hb_bytes + ell_bytes);  // 400 KB row counters

  const int sblocks = N_NODES / 32;               // 3125 (8 rows/wave)
  const int pblocks = (N_NODES + 255) / 256;      // 391

  // ---- one-pass prep: zero counters, scatter edges + convert x, pad ----
  hipMemsetAsync(cnt, 0, (size_t)N_NODES * sizeof(int), stream);
  scatter_convert<<<SCB + CVB, 1024, 0, stream>>>(
      (const float4*)x, (ushort4*)xbf, erow, ecol, evals, ell, cnt);
  pad_ell<<<pblocks, 256, 0, stream>>>(ell, cnt);

  // L1: bufA = bf16(A xbf)
  spmm_oct<<<sblocks, 256, 0, stream>>>(cnt, ell, xbf,
                                        bufA, nullptr, nullptr, nullptr, 0);
  // L2: bufB = bf16(A bufA)
  spmm_oct<<<sblocks, 256, 0, stream>>>(cnt, ell, bufA,
                                        bufB, nullptr, nullptr, nullptr, 0);
  // L3: out = A bufB + bufA + bufB   (f32 output)
  spmm_oct<<<sblocks, 256, 0, stream>>>(cnt, ell, bufB,
                                        nullptr, (float4*)out, bufA, bufB, 1);
}

// Round 5
// 282.744 us; speedup vs baseline: 1.0392x; 1.0392x over previous
//
#include <hip/hip_runtime.h>

#define N_NODES 100000
#define N_EDGES 1600000
#define D_FEAT  64

#define RSHIFT 8
#define RPB    256                              // rows per bucket
#define NBK    ((N_NODES + RPB - 1) / RPB)      // 391 row-buckets
#define CAP    5120                             // bucket edge capacity
#define EPB    4096                             // edges per bin block
#define KBLK   ((N_EDGES + EPB - 1) / EPB)      // 391 bin blocks
#define OROW   (NBK + 1)
#define CVB    ((N_NODES * D_FEAT / 4 + 1023) / 1024)  // 1563 convert blocks
#define NOCT   8                                // col ranges: col>>14 -> 0..6 used
#define SB2    ((N_NODES + 63) / 64)            // 1563 spmm blocks (64 rows each)

typedef float f32x2 __attribute__((ext_vector_type(2)));

__device__ __forceinline__ unsigned short f2bf(float f) {
  union { float f; unsigned int i; } v; v.f = f;
  unsigned int b = v.i;
  return (unsigned short)((b + 0x7FFFu + ((b >> 16) & 1u)) >> 16);  // RNE
}
__device__ __forceinline__ float ulo(int u) { return __int_as_float(u << 16); }
__device__ __forceinline__ float uhi(int u) { return __int_as_float(u & 0xFFFF0000); }
__device__ __forceinline__ f32x2 upk(int u) {  // {elem0, elem1} of a bf16 pair
  f32x2 r; r.x = ulo(u); r.y = uhi(u); return r;
}
__device__ __forceinline__ int pk(float a, float b) {
  return (int)f2bf(a) | ((int)f2bf(b) << 16);
}

// ---- fused: blocks [0,KBLK) bin edges; blocks [KBLK, KBLK+CVB) convert x ----
__global__ __launch_bounds__(1024) void convert_bin(
    const float4* __restrict__ xin, ushort4* __restrict__ xout,
    const int* __restrict__ erow, const int* __restrict__ ecol,
    const float* __restrict__ evals, int2* __restrict__ tmp,
    int* __restrict__ offs) {
  __shared__ int hist[NBK];
  __shared__ int sc[NBK];
  int t = threadIdx.x;
  int k = blockIdx.x;
  if (k >= KBLK) {                       // ---- convert path ----
    int i = (k - KBLK) * 1024 + t;
    if (i < N_NODES * D_FEAT / 4) {
      float4 v = xin[i];
      ushort4 o;
      o.x = f2bf(v.x); o.y = f2bf(v.y); o.z = f2bf(v.z); o.w = f2bf(v.w);
      xout[i] = o;
    }
    return;
  }
  // ---- bin path: block-local counting sort of 4096 edges by bucket ----
  if (t < NBK) hist[t] = 0;
  __syncthreads();
  int base = k * EPB;
  int nk = N_EDGES - base; if (nk > EPB) nk = EPB;
  int key[4], vb[4], rk[4], bk[4];
#pragma unroll
  for (int j = 0; j < 4; ++j) {
    int li = j * 1024 + t;
    bk[j] = -1;
    if (li < nk) {
      int e = base + li;
      int r = erow[e];
      key[j] = ((r & (RPB - 1)) << 17) | ecol[e];
      vb[j]  = __float_as_int(evals[e]);
      bk[j]  = r >> RSHIFT;
      rk[j]  = atomicAdd(&hist[bk[j]], 1);
    }
  }
  __syncthreads();
  if (t < NBK) sc[t] = hist[t];
  __syncthreads();
  for (int off = 1; off < NBK; off <<= 1) {
    int u = (t >= off && t < NBK) ? sc[t - off] : 0;
    __syncthreads();
    if (t < NBK) sc[t] += u;
    __syncthreads();
  }
  if (t < NBK) {
    int ex = sc[t] - hist[t];
    sc[t] = ex;
    offs[k * OROW + t] = ex;
  }
  if (t == 0) offs[k * OROW + NBK] = nk;
  __syncthreads();
#pragma unroll
  for (int j = 0; j < 4; ++j) {
    if (bk[j] >= 0) {
      int pos = sc[bk[j]] + rk[j];
      tmp[k * EPB + pos] = make_int2(key[j], vb[j]);
    }
  }
}

// ---- pass 2: per-(row, col-octant) counting sort within each 256-row bucket.
// Produces edges ordered by col-range within each row (the spmm pass
// structure needs this), plus packed u8 per-octant counts (cnt8) and the
// row's base offset. Octant = col >> 14 (7 ranges of 16384 cols = 2MB of x).
__global__ __launch_bounds__(512) void build_csr(
    const int2* __restrict__ tmp, const int* __restrict__ offs,
    int2* __restrict__ edges, int* __restrict__ row_beg,
    int2* __restrict__ cnt8) {
  __shared__ int hist[RPB * 8];
  __shared__ int cur[RPB * 8];
  __shared__ int sc[RPB];
  int b = blockIdx.x;
  int t = threadIdx.x;
  int o8 = t >> 3;         // 64 octets per block
  int ol = t & 7;
  for (int i = t; i < RPB * 8; i += 512) hist[i] = 0;
  __syncthreads();
  for (int k = o8; k < KBLK; k += 64) {
    int o0 = offs[k * OROW + b];
    int o1 = offs[k * OROW + b + 1];
    const int2* seg = tmp + k * EPB;
    for (int i = o0 + ol; i < o1; i += 8) {
      int key = seg[i].x;
      atomicAdd(&hist[((key >> 17) << 3) | ((key >> 14) & 7)], 1);
    }
  }
  __syncthreads();
  int v = 0, v2 = 0;
  if (t < RPB) {
#pragma unroll
    for (int o = 0; o < 8; ++o) v += hist[t * 8 + o];
    v2 = (v + 1) & ~1;     // even-padded row length (layout stability)
    sc[t] = v2;
  }
  __syncthreads();
  for (int off = 1; off < RPB; off <<= 1) {
    int u = (t >= off && t < RPB) ? sc[t - off] : 0;
    __syncthreads();
    if (t < RPB) sc[t] += u;
    __syncthreads();
  }
  if (t < RPB) {
    int excl2 = sc[t] - v2;
    int run = excl2;
    unsigned int lo = 0, hi = 0;
#pragma unroll
    for (int o = 0; o < 8; ++o) {
      cur[t * 8 + o] = run;
      int c = hist[t * 8 + o];
      run += c;
      unsigned int cc = (unsigned)(c > 255 ? 255 : c);   // P(clamp) ~ 0
      if (o < 4) lo |= cc << (8 * o); else hi |= cc << (8 * (o - 4));
    }
    int gr = b * RPB + t;
    if (gr < N_NODES) {
      row_beg[gr] = b * CAP + excl2;
      cnt8[gr] = make_int2((int)lo, (int)hi);
    }
  }
  __syncthreads();
  for (int k = o8; k < KBLK; k += 64) {
    int o0 = offs[k * OROW + b];
    int o1 = offs[k * OROW + b + 1];
    const int2* seg = tmp + k * EPB;
    for (int i = o0 + ol; i < o1; i += 8) {
      int2 ed = seg[i];
      int idx = ((ed.x >> 17) << 3) | ((ed.x >> 14) & 7);
      int pos = atomicAdd(&cur[idx], 1);
      edges[b * CAP + pos] = make_int2(ed.x & 0x1FFFF, ed.y);
    }
  }
}

// ---- SpMM, PASS-MAJOR over 7 column ranges of 16384 nodes (2MB of x each).
// All SB2=1563 blocks are co-resident (<= 8 blocks/CU), start together, and
// sweep ranges in soft lockstep -> the instantaneous gather window is ~1-2
// ranges (2-4MB), inside the 4MB per-XCD L2 -> avg gather latency ~halves
// (this is the MSHR*latency bound's only remaining lever).
// Block = 64 rows: 4 waves x 8 octet-rows x 2 register accumulator groups.
__global__ __launch_bounds__(256, 7) void spmm_pass(
    const int* __restrict__ row_beg, const int2* __restrict__ cnt8,
    const int2* __restrict__ edges, const int4* __restrict__ xq,
    int4* __restrict__ h_q, float4* __restrict__ out,
    const int4* __restrict__ add1, const int4* __restrict__ add2,
    int final_mode) {
  int t = threadIdx.x;
  int lane = t & 63;
  int oc = lane >> 3;      // 0..7: row within wave
  int ol = lane & 7;       // 0..7: which 16B of the 128B row
  int w = t >> 6;          // wave 0..3
  int r0 = blockIdx.x * 64 + w * 8 + oc;   // group 0 row
  int r1 = r0 + 32;                        // group 1 row
  bool val0 = r0 < N_NODES, val1 = r1 < N_NODES;
  int off0 = 0, off1 = 0;
  int2 k0 = make_int2(0, 0), k1 = make_int2(0, 0);
  if (val0) { off0 = row_beg[r0]; k0 = cnt8[r0]; }
  if (val1) { off1 = row_beg[r1]; k1 = cnt8[r1]; }
  f32x2 a0 = {0.f,0.f}, a1 = {0.f,0.f}, a2 = {0.f,0.f}, a3 = {0.f,0.f};
  f32x2 b0 = {0.f,0.f}, b1 = {0.f,0.f}, b2 = {0.f,0.f}, b3 = {0.f,0.f};

#pragma unroll
  for (int p = 0; p < 7; ++p) {
    int c0 = ((p < 4 ? (k0.x >> (8 * p)) : (k0.y >> (8 * (p - 4)))) & 255);
    for (int i = 0; i < c0; ++i) {
      int2 m = edges[off0 + i];
      int4 g = xq[(size_t)m.x * 8 + ol];
      float vv = __int_as_float(m.y);
      f32x2 vx = {vv, vv};
      a0 += vx * upk(g.x); a1 += vx * upk(g.y);
      a2 += vx * upk(g.z); a3 += vx * upk(g.w);
    }
    off0 += c0;
    int c1 = ((p < 4 ? (k1.x >> (8 * p)) : (k1.y >> (8 * (p - 4)))) & 255);
    for (int i = 0; i < c1; ++i) {
      int2 m = edges[off1 + i];
      int4 g = xq[(size_t)m.x * 8 + ol];
      float vv = __int_as_float(m.y);
      f32x2 vx = {vv, vv};
      b0 += vx * upk(g.x); b1 += vx * upk(g.y);
      b2 += vx * upk(g.z); b3 += vx * upk(g.w);
    }
    off1 += c1;
  }

#define EPILOG(row, valid, c0v, c1v, c2v, c3v) \
  if (valid) { \
    size_t oi = (size_t)(row) * 8 + ol; \
    if (final_mode) { \
      int4 r1v = add1[oi]; \
      int4 r2v = add2[oi]; \
      float4 lo, hi; \
      lo.x = (c0v).x + ulo(r1v.x) + ulo(r2v.x); \
      lo.y = (c0v).y + uhi(r1v.x) + uhi(r2v.x); \
      lo.z = (c1v).x + ulo(r1v.y) + ulo(r2v.y); \
      lo.w = (c1v).y + uhi(r1v.y) + uhi(r2v.y); \
      hi.x = (c2v).x + ulo(r1v.z) + ulo(r2v.z); \
      hi.y = (c2v).y + uhi(r1v.z) + uhi(r2v.z); \
      hi.z = (c3v).x + ulo(r1v.w) + ulo(r2v.w); \
      hi.w = (c3v).y + uhi(r1v.w) + uhi(r2v.w); \
      out[(size_t)(row) * 16 + ol * 2]     = lo; \
      out[(size_t)(row) * 16 + ol * 2 + 1] = hi; \
    } else { \
      int4 pq; \
      pq.x = pk((c0v).x, (c0v).y); \
      pq.y = pk((c1v).x, (c1v).y); \
      pq.z = pk((c2v).x, (c2v).y); \
      pq.w = pk((c3v).x, (c3v).y); \
      h_q[oi] = pq; \
    } \
  }

  EPILOG(r0, val0, a0, a1, a2, a3)
  EPILOG(r1, val1, b0, b1, b2, b3)
#undef EPILOG
}

extern "C" void kernel_launch(void* const* d_in, const int* in_sizes, int n_in,
                              void* d_out, int out_size, void* d_ws, size_t ws_size,
                              hipStream_t stream) {
  const float* x     = (const float*)d_in[0];
  const int*   erow  = (const int*)d_in[1];
  const int*   ecol  = (const int*)d_in[2];
  const float* evals = (const float*)d_in[3];
  float* out = (float*)d_out;

  const size_t hb_bytes   = (size_t)N_NODES * D_FEAT * 2;     // 12.8 MB (bf16)
  const size_t ecap_bytes = (size_t)NBK * CAP * sizeof(int2); // 16.0 MB
  char* ws = (char*)d_ws;
  int4* xbf   = (int4*)(ws);                       // 12.8 MB, live whole launch
  int4* bufA  = (int4*)(ws + hb_bytes);            // h1 (bf16)
  int2* tmp   = (int2*)(ws + hb_bytes);            // aliases bufA (build only)
  int4* bufB  = (int4*)(ws + 2 * hb_bytes);        // h2 (bf16)
  int*  offs  = (int*) (ws + 2 * hb_bytes);        // aliases bufB (build only)
  int2* edges = (int2*)(ws + 3 * hb_bytes);
  int*  row_beg = (int*)(ws + 3 * hb_bytes + ecap_bytes);
  int2* cnt8    = (int2*)(ws + 3 * hb_bytes + ecap_bytes + 400000);  // 800 KB

  // ---- fused convert + bin (1 dispatch), then octant-CSR finalize ----
  convert_bin<<<KBLK + CVB, 1024, 0, stream>>>(
      (const float4*)x, (ushort4*)xbf, erow, ecol, evals, tmp, offs);
  build_csr<<<NBK, 512, 0, stream>>>(tmp, offs, edges, row_beg, cnt8);

  // L1: bufA = bf16(A xbf)      (tmp dead after build)
  spmm_pass<<<SB2, 256, 0, stream>>>(row_beg, cnt8, edges, xbf,
                                     bufA, nullptr, nullptr, nullptr, 0);
  // L2: bufB = bf16(A bufA)     (offs dead)
  spmm_pass<<<SB2, 256, 0, stream>>>(row_beg, cnt8, edges, bufA,
                                     bufB, nullptr, nullptr, nullptr, 0);
  // L3: out = A bufB + bufA + bufB   (f32 output)
  spmm_pass<<<SB2, 256, 0, stream>>>(row_beg, cnt8, edges, bufB,
                                     nullptr, (float4*)out, bufA, bufB, 1);
}